// Round 1
// baseline (4693.999 us; speedup 1.0000x reference)
//
#include <hip/hip_runtime.h>

// LSTM stack: B=2048, T=512, IN=4, H=64, L=4, OUT=5.
// Strategy: one persistent kernel per layer. Each block owns NB=4 batch rows
// for the entire T loop (recurrence is independent per batch row -> no
// cross-block sync). Thread j (0..255) owns gate row j with its weight row
// (K = IN+H <= 128 floats) in REGISTERS (reused T*NB times). The shared
// [x_t ; h_{t-1}] vector lives in LDS and is read via same-address broadcast
// float4 loads (conflict-free). Gates round-trip through LDS for the
// pointwise c/h update (c in registers). Next-step input is prefetched into
// registers during the FMA loop. hs scratch ([T,B,H], 256 MiB in d_ws) is
// updated in place across layers. FC fused into layer 3 epilogue.

#define B_    2048
#define T_    512
#define H_    64
#define NB    4        // batch rows per block -> grid 512 = 2 blocks/CU
#define GATES 256
#define OUT_  5

__device__ __forceinline__ float sigf(float x) {
    // 1/(1+e^-x); v_exp+v_rcp ~1ulp each, fine vs 2.5e-3 abs threshold
    return __builtin_amdgcn_rcpf(1.0f + __expf(-x));
}
__device__ __forceinline__ float tanh_fast(float x) {
    // tanh(x) = 1 - 2/(e^{2x}+1); graceful at +/-inf
    return 1.0f - 2.0f * __builtin_amdgcn_rcpf(1.0f + __expf(2.0f * x));
}

template <int INP, bool WRITE_HS, bool DO_FC>
__global__ __launch_bounds__(256, 2) void lstm_layer_k(
    const float* __restrict__ in,     // INP==4: x [B,T,4]; else hs [T,B,H]
    const float* __restrict__ W_ih,   // [256, INP]
    const float* __restrict__ W_hh,   // [256, H]
    const float* __restrict__ b_ih,   // [256]
    const float* __restrict__ b_hh,   // [256]
    float* __restrict__ hs_out,       // [T,B,H] (may alias `in`; per-block in-place safe)
    const float* __restrict__ W_fc,   // [OUT_, H] (DO_FC only)
    const float* __restrict__ b_fc,   // [OUT_]
    float* __restrict__ out)          // [B, OUT_]
{
    constexpr int K = INP + H_;
    const int tid = threadIdx.x;
    const int b0  = blockIdx.x * NB;

    __shared__ alignas(16) float xh[NB][K];      // [x_t ; h] per batch row
    __shared__ alignas(16) float gbuf[NB][GATES];

    // ---- weights -> registers (row j of [W_ih | W_hh]) ----
    float wreg[K];
#pragma unroll
    for (int k = 0; k < INP; k += 4) {
        float4 v = *(const float4*)&W_ih[tid * INP + k];
        wreg[k] = v.x; wreg[k + 1] = v.y; wreg[k + 2] = v.z; wreg[k + 3] = v.w;
    }
#pragma unroll
    for (int k = 0; k < H_; k += 4) {
        float4 v = *(const float4*)&W_hh[tid * H_ + k];
        wreg[INP + k] = v.x; wreg[INP + k + 1] = v.y;
        wreg[INP + k + 2] = v.z; wreg[INP + k + 3] = v.w;
    }
    const float bias = b_ih[tid] + b_hh[tid];

    // update-phase mapping: one (batch,row) unit per thread
    const int ub = tid >> 6, uk = tid & 63;
    float c = 0.0f;
    xh[ub][INP + uk] = 0.0f;   // h_{-1} = 0 (h part of xh)

    // ---- input prefetch (1 elem/thread; 16 or 256 loader threads) ----
    constexpr int NLOAD = NB * INP;
    const bool loader = (tid < NLOAD);
    const int lb = tid / INP, li = tid % INP;
    float inreg = 0.0f;
    if (loader) {
        inreg = (INP == 4) ? in[(b0 + lb) * (T_ * INP) + li]
                           : in[(b0 + lb) * H_ + li];     // t=0 slice
    }

    for (int t = 0; t < T_; ++t) {
        if (loader) xh[lb][li] = inreg;
        __syncthreads();
        // prefetch t+1 while FMAs run
        if (loader && t + 1 < T_) {
            inreg = (INP == 4)
                  ? in[(b0 + lb) * (T_ * INP) + (t + 1) * INP + li]
                  : in[(t + 1) * (B_ * H_) + (b0 + lb) * H_ + li];
        }

        // ---- gate GEMV: acc_b = bias + wreg . xh[b][:] ----
        float a0 = bias, a1 = bias, a2 = bias, a3 = bias;
#pragma unroll
        for (int kq = 0; kq < K; kq += 4) {
            float4 v0 = *(const float4*)&xh[0][kq];
            float4 v1 = *(const float4*)&xh[1][kq];
            float4 v2 = *(const float4*)&xh[2][kq];
            float4 v3 = *(const float4*)&xh[3][kq];
            a0 = fmaf(wreg[kq], v0.x, a0); a0 = fmaf(wreg[kq + 1], v0.y, a0);
            a0 = fmaf(wreg[kq + 2], v0.z, a0); a0 = fmaf(wreg[kq + 3], v0.w, a0);
            a1 = fmaf(wreg[kq], v1.x, a1); a1 = fmaf(wreg[kq + 1], v1.y, a1);
            a1 = fmaf(wreg[kq + 2], v1.z, a1); a1 = fmaf(wreg[kq + 3], v1.w, a1);
            a2 = fmaf(wreg[kq], v2.x, a2); a2 = fmaf(wreg[kq + 1], v2.y, a2);
            a2 = fmaf(wreg[kq + 2], v2.z, a2); a2 = fmaf(wreg[kq + 3], v2.w, a2);
            a3 = fmaf(wreg[kq], v3.x, a3); a3 = fmaf(wreg[kq + 1], v3.y, a3);
            a3 = fmaf(wreg[kq + 2], v3.z, a3); a3 = fmaf(wreg[kq + 3], v3.w, a3);
        }
        gbuf[0][tid] = a0; gbuf[1][tid] = a1; gbuf[2][tid] = a2; gbuf[3][tid] = a3;
        __syncthreads();

        // ---- pointwise update (gate order i,f,g,o) ----
        const float gi = gbuf[ub][uk];
        const float gf = gbuf[ub][64 + uk];
        const float gg = gbuf[ub][128 + uk];
        const float go = gbuf[ub][192 + uk];
        c = sigf(gf) * c + sigf(gi) * tanh_fast(gg);
        const float h = sigf(go) * tanh_fast(c);
        xh[ub][INP + uk] = h;
        if (WRITE_HS) hs_out[t * (B_ * H_) + (b0 + ub) * H_ + uk] = h;
        // no barrier needed here: next iter only writes disjoint LDS regions
        // before the top barrier
    }

    if (DO_FC) {
        __syncthreads();
        if (tid < NB * OUT_) {
            const int b = tid / OUT_, o = tid % OUT_;
            float a = b_fc[o];
#pragma unroll
            for (int k = 0; k < H_; ++k)
                a = fmaf(xh[b][INP + k], W_fc[o * H_ + k], a);
            out[(b0 + b) * OUT_ + o] = a;
        }
    }
}

extern "C" void kernel_launch(void* const* d_in, const int* in_sizes, int n_in,
                              void* d_out, int out_size, void* d_ws, size_t ws_size,
                              hipStream_t stream) {
    const float* x     = (const float*)d_in[0];  // [B,T,4]
    const float* W_ih0 = (const float*)d_in[1];  // [256,4]
    const float* W_ihr = (const float*)d_in[2];  // [3,256,64]
    const float* W_hh  = (const float*)d_in[3];  // [4,256,64]
    const float* b_ih  = (const float*)d_in[4];  // [4,256]
    const float* b_hh  = (const float*)d_in[5];  // [4,256]
    const float* W_fc  = (const float*)d_in[6];  // [5,64]
    const float* b_fc  = (const float*)d_in[7];  // [5]
    float* out = (float*)d_out;                  // [B,5]
    float* hs  = (float*)d_ws;                   // [T,B,H] = 256 MiB scratch

    const int WS = 256 * 64;  // per-layer W_hh / W_ihr stride
    dim3 grid(B_ / NB), block(256);

    // layer 0: x -> hs
    lstm_layer_k<4, true, false><<<grid, block, 0, stream>>>(
        x, W_ih0, W_hh, b_ih, b_hh, hs, nullptr, nullptr, nullptr);
    // layers 1,2: hs -> hs (in-place safe: each block only touches its own b-rows)
    lstm_layer_k<64, true, false><<<grid, block, 0, stream>>>(
        hs, W_ihr, W_hh + WS, b_ih + 256, b_hh + 256, hs, nullptr, nullptr, nullptr);
    lstm_layer_k<64, true, false><<<grid, block, 0, stream>>>(
        hs, W_ihr + WS, W_hh + 2 * WS, b_ih + 512, b_hh + 512, hs, nullptr, nullptr, nullptr);
    // layer 3: hs -> (no hs write) + fused FC on t = T-1
    lstm_layer_k<64, false, true><<<grid, block, 0, stream>>>(
        hs, W_ihr + 2 * WS, W_hh + 3 * WS, b_ih + 768, b_hh + 768, nullptr, W_fc, b_fc, out);
}

// Round 2
// 2677.948 us; speedup vs baseline: 1.7528x; 1.7528x over previous
//
#include <hip/hip_runtime.h>

// Stacked LSTM B=2048,T=512,IN=4,H=64,L=4,OUT=5 — MFMA version.
// Per block: NB=16 batch rows for the whole T loop (grid 128, 1 block/CU-ish).
// gates[m][n] = sum_k xh[m][k] * Wcat[n][k], computed as 16x16x32 bf16 MFMAs
// with hi/lo fp32->bf16 split (3 MFMAs: Ah*Bh + Al*Bh + Ah*Bl) for ~2^-18
// relative precision. Weights stationary in registers as B-frags. Wave w owns
// N-tiles {w,4+w,8+w,12+w} so each lane holds gates i,f,g,o of hidden unit
// u=16w+(lane&15) for 4 batches -> pointwise update fully in registers.
// A operand ([h ; x_t], K=128) staged in an 8KB LDS buffer per step.
// Layer 0: K=64 (h only) MFMA + K=4 input GEMV on VALU. FC fused in layer 3.

#define B_    2048
#define T_    512
#define H_    64
#define NB    16
#define OUT_  5

typedef __attribute__((ext_vector_type(8))) short bf16x8;
typedef __attribute__((ext_vector_type(4))) float f32x4;

__device__ __forceinline__ float sigf(float x) {
    return __builtin_amdgcn_rcpf(1.0f + __expf(-x));
}
__device__ __forceinline__ float tanh_fast(float x) {
    return 1.0f - 2.0f * __builtin_amdgcn_rcpf(1.0f + __expf(2.0f * x));
}
// fp32 -> bf16 (RNE) and back, finite values only
__device__ __forceinline__ unsigned short f2bf(float x) {
    unsigned u = __float_as_uint(x);
    u += 0x7fffu + ((u >> 16) & 1u);
    return (unsigned short)(u >> 16);
}
__device__ __forceinline__ float bf2f(unsigned short b) {
    return __uint_as_float(((unsigned)b) << 16);
}

template <bool L0, bool WRITE_HS, bool DO_FC>
__global__ __launch_bounds__(256, 1) void lstm_mfma_k(
    const float* __restrict__ in,     // L0: x [B,T,4]; else hs_prev [T,B,H]
    const float* __restrict__ W_ih,   // L0: [256,4]; else [256,64]
    const float* __restrict__ W_hh,   // [256,64]
    const float* __restrict__ b_ih,
    const float* __restrict__ b_hh,
    float* __restrict__ hs_out,       // [T,B,H]
    const float* __restrict__ W_fc,   // [OUT_,64]
    const float* __restrict__ b_fc,   // [OUT_]
    float* __restrict__ out)          // [B,OUT_]
{
    constexpr int KT = L0 ? 2 : 4;    // K tiles of 32: K=64 (h) or 128 ([h;x])
    const int tid  = threadIdx.x;
    const int lane = tid & 63;
    const int wv   = tid >> 6;        // wave 0..3
    const int q    = lane >> 4;       // quad
    const int ln   = lane & 15;
    const int u    = wv * 16 + ln;    // hidden unit owned by this lane
    const int b0   = blockIdx.x * NB;

    // A staging: [hilo][k-octet(16)][batch row(16)][j(8)] bf16 -> 8 KB
    __shared__ alignas(16) unsigned short aBuf[2][16][16][8];
    __shared__ alignas(16) float xbuf[NB][4];   // L0: x_t staging

    // ---- weights -> B-fragments in registers (hi/lo) ----
    // B-frag for (nti,kt): lane holds Wcat[n = nti*64+u][k = kt*32+q*8 .. +8]
    // Wcat: k in [0,64) -> W_hh, k in [64,128) -> W_ih (layers>=1)
    bf16x8 Bh[4][KT], Bl[4][KT];
#pragma unroll
    for (int nti = 0; nti < 4; ++nti) {
        const int n = nti * 64 + u;
#pragma unroll
        for (int kt = 0; kt < KT; ++kt) {
            const int k = kt * 32 + q * 8;
            const float* src = (!L0 && k >= 64) ? (W_ih + n * 64 + (k - 64))
                                                : (W_hh + n * 64 + k);
            float4 v0 = *(const float4*)(src);
            float4 v1 = *(const float4*)(src + 4);
            float vv[8] = {v0.x, v0.y, v0.z, v0.w, v1.x, v1.y, v1.z, v1.w};
            bf16x8 fh, fl;
#pragma unroll
            for (int j = 0; j < 8; ++j) {
                unsigned short hb = f2bf(vv[j]);
                fh[j] = (short)hb;
                fl[j] = (short)f2bf(vv[j] - bf2f(hb));
            }
            Bh[nti][kt] = fh;
            Bl[nti][kt] = fl;
        }
    }

    float bias[4];
#pragma unroll
    for (int nti = 0; nti < 4; ++nti)
        bias[nti] = b_ih[nti * 64 + u] + b_hh[nti * 64 + u];

    float4 wi0[4];
    if (L0) {
#pragma unroll
        for (int nti = 0; nti < 4; ++nti)
            wi0[nti] = *(const float4*)(W_ih + (nti * 64 + u) * 4);
    }

    float c[4] = {0.f, 0.f, 0.f, 0.f};
    float h[4] = {0.f, 0.f, 0.f, 0.f};

    // ---- input prefetch, 2 steps deep ----
    const int rb = tid >> 4, cb = tid & 15;
    float4 pf[2];
    if (!L0) {
        pf[0] = *(const float4*)(in + 0 * (B_ * H_) + (b0 + rb) * H_ + cb * 4);
        pf[1] = *(const float4*)(in + 1 * (B_ * H_) + (b0 + rb) * H_ + cb * 4);
    } else if (tid < NB) {
        pf[0] = *(const float4*)(in + (b0 + tid) * (T_ * 4) + 0);
        pf[1] = *(const float4*)(in + (b0 + tid) * (T_ * 4) + 4);
    }

#pragma unroll 1
    for (int t = 0; t < T_; ++t) {
        // ---- P1: stage A operand (h(t-1) into octets 0..7, x_t into 8..15) ----
#pragma unroll
        for (int r = 0; r < 4; ++r) {
            const int m = q * 4 + r;
            unsigned short hb = f2bf(h[r]);
            aBuf[0][u >> 3][m][u & 7] = hb;
            aBuf[1][u >> 3][m][u & 7] = f2bf(h[r] - bf2f(hb));
        }
        if (!L0) {
            float4 v = pf[t & 1];
            ushort4 hv, lv;
            hv.x = f2bf(v.x); lv.x = f2bf(v.x - bf2f(hv.x));
            hv.y = f2bf(v.y); lv.y = f2bf(v.y - bf2f(hv.y));
            hv.z = f2bf(v.z); lv.z = f2bf(v.z - bf2f(hv.z));
            hv.w = f2bf(v.w); lv.w = f2bf(v.w - bf2f(hv.w));
            const int oct = 8 + (cb >> 1), j = (cb & 1) * 4;
            *(ushort4*)&aBuf[0][oct][rb][j] = hv;
            *(ushort4*)&aBuf[1][oct][rb][j] = lv;
        } else if (tid < NB) {
            *(float4*)&xbuf[tid][0] = pf[t & 1];
        }
        __syncthreads();

        // ---- prefetch t+2 (lands well before it's consumed) ----
        if (!L0) {
            if (t + 2 < T_)
                pf[t & 1] = *(const float4*)(in + (t + 2) * (B_ * H_) + (b0 + rb) * H_ + cb * 4);
        } else if (tid < NB && t + 2 < T_) {
            pf[t & 1] = *(const float4*)(in + (b0 + tid) * (T_ * 4) + (t + 2) * 4);
        }

        // ---- A fragments from LDS ----
        bf16x8 Ah[KT], Al[KT];
#pragma unroll
        for (int kt = 0; kt < KT; ++kt) {
            Ah[kt] = *(const bf16x8*)&aBuf[0][kt * 4 + q][ln][0];
            Al[kt] = *(const bf16x8*)&aBuf[1][kt * 4 + q][ln][0];
        }

        // ---- MFMA: gates[m][nti*64+u] ----
        f32x4 acc[4];
#pragma unroll
        for (int nti = 0; nti < 4; ++nti) acc[nti] = (f32x4){0.f, 0.f, 0.f, 0.f};
#pragma unroll
        for (int kt = 0; kt < KT; ++kt) {
#pragma unroll
            for (int nti = 0; nti < 4; ++nti) {
                acc[nti] = __builtin_amdgcn_mfma_f32_16x16x32_bf16(Ah[kt], Bh[nti][kt], acc[nti], 0, 0, 0);
                acc[nti] = __builtin_amdgcn_mfma_f32_16x16x32_bf16(Al[kt], Bh[nti][kt], acc[nti], 0, 0, 0);
                acc[nti] = __builtin_amdgcn_mfma_f32_16x16x32_bf16(Ah[kt], Bl[nti][kt], acc[nti], 0, 0, 0);
            }
        }

        // ---- pointwise, fully in registers (lane owns unit u, 4 batches) ----
#pragma unroll
        for (int r = 0; r < 4; ++r) {
            const int m = q * 4 + r;
            float gi = acc[0][r] + bias[0];
            float gf = acc[1][r] + bias[1];
            float gg = acc[2][r] + bias[2];
            float go = acc[3][r] + bias[3];
            if (L0) {
                float4 xv = *(const float4*)&xbuf[m][0];
                gi = fmaf(wi0[0].x, xv.x, fmaf(wi0[0].y, xv.y, fmaf(wi0[0].z, xv.z, fmaf(wi0[0].w, xv.w, gi))));
                gf = fmaf(wi0[1].x, xv.x, fmaf(wi0[1].y, xv.y, fmaf(wi0[1].z, xv.z, fmaf(wi0[1].w, xv.w, gf))));
                gg = fmaf(wi0[2].x, xv.x, fmaf(wi0[2].y, xv.y, fmaf(wi0[2].z, xv.z, fmaf(wi0[2].w, xv.w, gg))));
                go = fmaf(wi0[3].x, xv.x, fmaf(wi0[3].y, xv.y, fmaf(wi0[3].z, xv.z, fmaf(wi0[3].w, xv.w, go))));
            }
            c[r] = sigf(gf) * c[r] + sigf(gi) * tanh_fast(gg);
            h[r] = sigf(go) * tanh_fast(c[r]);
            if (WRITE_HS) hs_out[t * (B_ * H_) + (b0 + m) * H_ + u] = h[r];
        }
        __syncthreads();   // aBuf/xbuf reads done before next P1 overwrites
    }

    if (DO_FC) {
        float* hf = (float*)&aBuf[0][0][0][0];   // 16x64 f32 = 4 KB, reuse LDS
#pragma unroll
        for (int r = 0; r < 4; ++r) hf[(q * 4 + r) * H_ + u] = h[r];
        __syncthreads();
        if (tid < NB * OUT_) {
            const int b = tid / OUT_, o = tid % OUT_;
            float a = b_fc[o];
#pragma unroll
            for (int k = 0; k < H_; ++k)
                a = fmaf(hf[b * H_ + k], W_fc[o * H_ + k], a);
            out[(b0 + b) * OUT_ + o] = a;
        }
    }
}

extern "C" void kernel_launch(void* const* d_in, const int* in_sizes, int n_in,
                              void* d_out, int out_size, void* d_ws, size_t ws_size,
                              hipStream_t stream) {
    const float* x     = (const float*)d_in[0];  // [B,T,4]
    const float* W_ih0 = (const float*)d_in[1];  // [256,4]
    const float* W_ihr = (const float*)d_in[2];  // [3,256,64]
    const float* W_hh  = (const float*)d_in[3];  // [4,256,64]
    const float* b_ih  = (const float*)d_in[4];  // [4,256]
    const float* b_hh  = (const float*)d_in[5];  // [4,256]
    const float* W_fc  = (const float*)d_in[6];  // [5,64]
    const float* b_fc  = (const float*)d_in[7];  // [5]
    float* out = (float*)d_out;                  // [B,5]
    float* hs  = (float*)d_ws;                   // [T,B,H] scratch (256 MiB)

    const int WS = 256 * 64;
    dim3 grid(B_ / NB), block(256);

    lstm_mfma_k<true, true, false><<<grid, block, 0, stream>>>(
        x, W_ih0, W_hh, b_ih, b_hh, hs, nullptr, nullptr, nullptr);
    lstm_mfma_k<false, true, false><<<grid, block, 0, stream>>>(
        hs, W_ihr, W_hh + WS, b_ih + 256, b_hh + 256, hs, nullptr, nullptr, nullptr);
    lstm_mfma_k<false, true, false><<<grid, block, 0, stream>>>(
        hs, W_ihr + WS, W_hh + 2 * WS, b_ih + 512, b_hh + 512, hs, nullptr, nullptr, nullptr);
    lstm_mfma_k<false, false, true><<<grid, block, 0, stream>>>(
        hs, W_ihr + 2 * WS, W_hh + 3 * WS, b_ih + 768, b_hh + 768, nullptr, W_fc, b_fc, out);
}